// Round 5
// baseline (151.512 us; speedup 1.0000x reference)
//
#include <hip/hip_runtime.h>
#include <math.h>

// RUL loss: out = theta * sum(score(diff)) + (1-theta) * sqrt(mean(diff^2))
// score(d) = (d<0 ? exp(-d/13) : exp(d/10)) - 1
// N = 16777216 fp32. Memory-bound: 134 MB logical read (~half L3-resident).
//
// R4: R3's forced-MLP inline asm crashed: no earlyclobber + per-load 64-bit
// address pairs => allocator reused an in-flight load's dst as a later load's
// address (it models asm outputs as synchronous; VMEM is async). Fix:
//  - single shared 32-bit voffset VGPR + uniform SGPR base per load
//    (global_load_dwordx4 vdst, voff, s[base]) -- no per-load addr VGPRs
//  - "=&v" earlyclobber on every dst
//  - explicit s_waitcnt vmcnt(0), then volatile identity asm on each value
//    so no consumer ALU can be hoisted above the wait.
// 16 dwordx4 (16 KB/wave) in flight, compiler-proof.

#define RUL_N 16777216
#define PART_BLOCKS 2048
#define BLOCK_THREADS 256
#define GRID_THREADS (PART_BLOCKS * BLOCK_THREADS)
#define ITERS ((RUL_N / 4) / GRID_THREADS)   // = 8, compile-time constant

typedef float v4f __attribute__((ext_vector_type(4)));

// vdst <- mem[sbase + voff]; voff is a 32-bit byte offset VGPR, sbase uniform.
#define GLOAD4(dst, voff, sbase) \
    asm volatile("global_load_dwordx4 %0, %1, %2" \
                 : "=&v"(dst) : "v"(voff), "s"(sbase))

// Pin value's availability after the preceding volatile waitcnt.
#define PIN(x) asm volatile("" : "+v"(x))

__global__ __launch_bounds__(BLOCK_THREADS, 2) void rul_partial_kernel(
    const float* __restrict__ pred,
    const float* __restrict__ tru,
    float* __restrict__ partials /* [2 * PART_BLOCKS] */) {

    const int tid = blockIdx.x * BLOCK_THREADS + threadIdx.x;
    const int v_byte = tid * 16;   // byte offset of this thread's float4

    v4f p[ITERS];
    v4f t[ITERS];

    // ---- load phase: 16 dwordx4 issued back-to-back, 16 KB/wave in flight ----
#pragma unroll
    for (int k = 0; k < ITERS; ++k) {
        GLOAD4(p[k], v_byte, pred + (size_t)k * GRID_THREADS * 4);
        GLOAD4(t[k], v_byte, tru  + (size_t)k * GRID_THREADS * 4);
    }
    asm volatile("s_waitcnt vmcnt(0)" ::: "memory");
#pragma unroll
    for (int k = 0; k < ITERS; ++k) { PIN(p[k]); PIN(t[k]); }

    // ---- compute phase ----
    float s_score0 = 0.0f, s_score1 = 0.0f;
    float s_sq0 = 0.0f, s_sq1 = 0.0f;
#pragma unroll
    for (int k = 0; k < ITERS; ++k) {
        float d0 = p[k][0] - t[k][0];
        float d1 = p[k][1] - t[k][1];
        float d2 = p[k][2] - t[k][2];
        float d3 = p[k][3] - t[k][3];

        float e0 = __expf(d0 * (d0 < 0.0f ? (-1.0f / 13.0f) : (1.0f / 10.0f)));
        float e1 = __expf(d1 * (d1 < 0.0f ? (-1.0f / 13.0f) : (1.0f / 10.0f)));
        float e2 = __expf(d2 * (d2 < 0.0f ? (-1.0f / 13.0f) : (1.0f / 10.0f)));
        float e3 = __expf(d3 * (d3 < 0.0f ? (-1.0f / 13.0f) : (1.0f / 10.0f)));

        s_score0 += (e0 - 1.0f) + (e1 - 1.0f);
        s_score1 += (e2 - 1.0f) + (e3 - 1.0f);
        s_sq0 += d0 * d0 + d1 * d1;
        s_sq1 += d2 * d2 + d3 * d3;
    }
    float s_score = s_score0 + s_score1;
    float s_sq = s_sq0 + s_sq1;

    // wave-64 reduce
#pragma unroll
    for (int off = 32; off > 0; off >>= 1) {
        s_score += __shfl_down(s_score, off);
        s_sq += __shfl_down(s_sq, off);
    }

    __shared__ float sm_score[BLOCK_THREADS / 64];
    __shared__ float sm_sq[BLOCK_THREADS / 64];
    const int wave = threadIdx.x >> 6;
    const int lane = threadIdx.x & 63;
    if (lane == 0) {
        sm_score[wave] = s_score;
        sm_sq[wave] = s_sq;
    }
    __syncthreads();
    if (threadIdx.x == 0) {
        float a = 0.0f, b = 0.0f;
#pragma unroll
        for (int w = 0; w < BLOCK_THREADS / 64; ++w) {
            a += sm_score[w];
            b += sm_sq[w];
        }
        partials[blockIdx.x] = a;
        partials[PART_BLOCKS + blockIdx.x] = b;
    }
}

__global__ __launch_bounds__(BLOCK_THREADS) void rul_finalize_kernel(
    const float* __restrict__ partials,
    const float* __restrict__ theta_ptr,
    float* __restrict__ out) {
    float a = 0.0f, b = 0.0f;
#pragma unroll
    for (int i = threadIdx.x; i < PART_BLOCKS; i += BLOCK_THREADS) {
        a += partials[i];
        b += partials[PART_BLOCKS + i];
    }
#pragma unroll
    for (int off = 32; off > 0; off >>= 1) {
        a += __shfl_down(a, off);
        b += __shfl_down(b, off);
    }
    __shared__ float sm_a[BLOCK_THREADS / 64];
    __shared__ float sm_b[BLOCK_THREADS / 64];
    const int wave = threadIdx.x >> 6;
    const int lane = threadIdx.x & 63;
    if (lane == 0) {
        sm_a[wave] = a;
        sm_b[wave] = b;
    }
    __syncthreads();
    if (threadIdx.x == 0) {
        float sa = 0.0f, sb = 0.0f;
#pragma unroll
        for (int w = 0; w < BLOCK_THREADS / 64; ++w) {
            sa += sm_a[w];
            sb += sm_b[w];
        }
        float theta = theta_ptr[0];
        float rmse = sqrtf(sb * (1.0f / (float)RUL_N));
        out[0] = theta * sa + (1.0f - theta) * rmse;
    }
}

extern "C" void kernel_launch(void* const* d_in, const int* in_sizes, int n_in,
                              void* d_out, int out_size, void* d_ws, size_t ws_size,
                              hipStream_t stream) {
    const float* pred = (const float*)d_in[0];
    const float* tru = (const float*)d_in[1];
    const float* theta = (const float*)d_in[2];
    float* out = (float*)d_out;
    float* partials = (float*)d_ws; // needs 2 * PART_BLOCKS * 4 = 16 KB

    rul_partial_kernel<<<PART_BLOCKS, BLOCK_THREADS, 0, stream>>>(pred, tru, partials);
    rul_finalize_kernel<<<1, BLOCK_THREADS, 0, stream>>>(partials, theta, out);
}